// Round 15
// baseline (2534.019 us; speedup 1.0000x reference)
//
#include <hip/hip_runtime.h>
#include <hip/hip_cooperative_groups.h>

namespace cg = cooperative_groups;

typedef unsigned short u16;
typedef unsigned int   u32;
typedef unsigned long long u64;
typedef __attribute__((ext_vector_type(8))) short short8;
typedef __attribute__((ext_vector_type(4))) float f32x4;

#define BB   64
#define TT   256
#define II   512
#define HH   1024
#define KCB  512
#define GH   4096
#define KTOT 1536

#define BPAD 1544   // u16 elems per B row (3088 B stride)

// ws layout (float units):
//   [0 .. 6291456)        WT f32 [4096][1536] (dead after B-split)
//   [.. +131072)          h: 2 parities x (hi plane 65536 u16 + lo plane 65536 u16), SLOT-indexed
//   [.. +32768)           dist^2 [64][512] f32
//   [.. +256)             flags: 8 chunks x 32 u32 (one 128B line per chunk)
//   [.. +544)             barT: tail barrier, 17 lines x 32 u32
#define WS_WT   0
#define WS_H    (GH*KTOT)
#define WS_DIST (WS_H + 131072)
#define WS_FLG  (WS_DIST + BB*KCB)
#define WS_BART (WS_FLG + 8*32)

#define LD_AG(p)   __hip_atomic_load((p), __ATOMIC_RELAXED, __HIP_MEMORY_SCOPE_AGENT)
#define ST_AG(p,v) __hip_atomic_store((p), (v), __ATOMIC_RELAXED, __HIP_MEMORY_SCOPE_AGENT)

__device__ __forceinline__ float sigf(float x){ return 1.0f/(1.0f+expf(-x)); }
__device__ __forceinline__ u16 bf16r(float f){ u32 u = __float_as_uint(f); u += 0x7FFFu + ((u>>16)&1u); return (u16)(u>>16); }
__device__ __forceinline__ float bf16f(u16 h){ return __uint_as_float(((u32)h)<<16); }

// ---- block-level tail barrier (rounds 5-14 proven) ----
__device__ __forceinline__ void bar_arrive(u32* bar, int bid, int tid, int e){
    asm volatile("s_waitcnt vmcnt(0)" ::: "memory");
    __syncthreads();
    if (tid == 0) {
        u32 old = atomicAdd(bar + (bid & 7) * 32, 1u);
        if (old == (u32)(e * 32 - 1)) {
            u32 old2 = atomicAdd(bar + 8 * 32, 1u);
            if (old2 == (u32)(e * 8 - 1)) {
                #pragma unroll
                for (int gg = 0; gg < 8; ++gg)
                    ST_AG(bar + (9 + gg) * 32, (u32)e);
            }
        }
    }
}
__device__ __forceinline__ void bar_wait(u32* bar, int bid, int tid, int e){
    if (tid == 0) {
        while ((int)LD_AG(bar + (9 + (bid & 7)) * 32) < e)
            __builtin_amdgcn_s_sleep(1);
        __builtin_amdgcn_fence(__ATOMIC_ACQUIRE, "agent");
    }
    __syncthreads();
}

__global__ __launch_bounds__(512, 1)
void lstm_vq(const float* __restrict__ seq, const int* __restrict__ nit,
             const float* __restrict__ Wx, const float* __restrict__ Wh,
             const float* __restrict__ bias, const float* __restrict__ cb,
             float* __restrict__ out, float* __restrict__ ws)
{
    cg::grid_group grid = cg::this_grid();
    __shared__ __align__(16) u16 bHi[16*BPAD];   // 49408 B (one-time use)
    __shared__ __align__(16) u16 bLo[16*BPAD];   // 49408 B (one-time use)
    __shared__ __align__(16) float exs[8*1024];  // 32768 B: [kslice][slot][col]
    __shared__ int permL[64], snitL[64];         // slot -> phys row / sorted nit
    __shared__ int sBest;

    const int tid = threadIdx.x;
    const int l   = tid & 63;
    const int w   = tid >> 6;        // 0..7 = k-slice / h-chunk owner
    const int bid = (int)blockIdx.x;

    float* WT   = ws + WS_WT;
    u16*   hbuf = (u16*)(ws + WS_H);             // 2 parities x 131072 u16
    float* dist = ws + WS_DIST;
    u32*   flg  = (u32*)(ws + WS_FLG);
    u32*   barT = (u32*)(ws + WS_BART);
    float* qz   = out + BB;
    float* uq   = out + BB + BB*HH;

    if (bid == 0) {
        for (int i = tid; i < 8*32 + 17*32; i += 512) ST_AG(flg + i, 0u);
    }

    // ---------------- one-time: WT[zcol][k] = W[k][zcol] ----------------
    {
        const int c0 = bid * 16;
        float* tile = (float*)bHi;               // 16 x 68 f32 scratch (pre-B-split)
        for (int kt = 0; kt < KTOT; kt += 64) {
            __syncthreads();
            #pragma unroll
            for (int ii2 = 0; ii2 < 2; ++ii2) {
                int ky = ii2*32 + (tid>>4);      // 0..63
                int cx = tid & 15;
                int kk = kt + ky;
                float v = (kk < II) ? Wx[(size_t)kk*GH + c0 + cx]
                                    : Wh[(size_t)(kk-II)*GH + c0 + cx];
                tile[cx*68 + ky] = v;
            }
            __syncthreads();
            {
                int cx = tid >> 5;               // 0..15
                int k2 = (tid & 31) * 2;         // 0..62
                WT[(size_t)(c0+cx)*KTOT + kt + k2]     = tile[cx*68 + k2];
                WT[(size_t)(c0+cx)*KTOT + kt + k2 + 1] = tile[cx*68 + k2 + 1];
            }
        }
        grid.sync();   // full fences: WT visible; orders flag/barT reset
    }

    // ---------------- one-time: split this block's 16 z-cols into bHi/bLo ----------------
    {
        __syncthreads();
        const int n  = tid >> 5;                              // 0..15
        const int zc = ((n>>2)<<10) + (bid<<2) + (n&3);
        const float* wr = WT + (size_t)zc*KTOT;
        for (int k = (tid&31)*8; k < KTOT; k += 256) {
            f32x4 v0 = *(const f32x4*)(wr + k);
            f32x4 v1 = *(const f32x4*)(wr + k + 4);
            short8 ph, pl;
            #pragma unroll
            for (int e = 0; e < 8; ++e) {
                float fv = (e<4) ? v0[e] : v1[e-4];
                u16 hb = bf16r(fv);
                ph[e] = (short)hb;
                pl[e] = (short)bf16r(fv - bf16f(hb));
            }
            *(short8*)&bHi[n*BPAD + k] = ph;
            *(short8*)&bLo[n*BPAD + k] = pl;
        }
    }

    // ---------------- one-time: sorted-slot permutation (rows indep; sort by nit desc) ----------------
    {
        if (w == 0) {
            int ni = nit[l];
            int r  = 0;
            #pragma unroll
            for (int j = 0; j < 64; ++j) {
                int nj = __shfl(ni, j, 64);
                r += (nj > ni || (nj == ni && j < l)) ? 1 : 0;
            }
            permL[r] = l;         // slot r holds physical row l
            snitL[r] = ni;        // sorted (desc) nit
        }
        __syncthreads();          // covers B-split LDS writes AND permL/snitL
    }

    // ---------------- per-lane LOOP-INVARIANT B fragments -> named registers ----------------
    const int ag  = (l>>4)<<3;               // k sub-offset within K=32 slice
    const int bn  = l & 15;                  // B col this lane reads
    const int xk0 = (w<<6) + ag;             // x-phase k base (this wave)
    const int hk0 = 512 + (w<<7) + ag;       // h-phase k base (chunk w)
    const short8 bx0h = *(const short8*)&bHi[bn*BPAD + xk0];
    const short8 bx0l = *(const short8*)&bLo[bn*BPAD + xk0];
    const short8 bx1h = *(const short8*)&bHi[bn*BPAD + xk0 + 32];
    const short8 bx1l = *(const short8*)&bLo[bn*BPAD + xk0 + 32];
    const short8 bh0h = *(const short8*)&bHi[bn*BPAD + hk0];
    const short8 bh0l = *(const short8*)&bLo[bn*BPAD + hk0];
    const short8 bh1h = *(const short8*)&bHi[bn*BPAD + hk0 + 32];
    const short8 bh1l = *(const short8*)&bLo[bn*BPAD + hk0 + 32];
    const short8 bh2h = *(const short8*)&bHi[bn*BPAD + hk0 + 64];
    const short8 bh2l = *(const short8*)&bLo[bn*BPAD + hk0 + 64];
    const short8 bh3h = *(const short8*)&bHi[bn*BPAD + hk0 + 96];
    const short8 bh3l = *(const short8*)&bLo[bn*BPAD + hk0 + 96];

    // ---------------- per-thread roles ----------------
    const int rEx  = (tid & 255) >> 2;           // gate slot (tid<256)
    const int ccEx = tid & 3;
    const int hcol = (bid<<2) + ccEx;
    const int prG  = permL[rEx];                 // physical row of my gate slot
    const int myNs = snitL[rEx];                 // its n_iter

    const int tmx1 = __builtin_amdgcn_readfirstlane(snitL[16]);
    const int tmx2 = __builtin_amdgcn_readfirstlane(snitL[32]);
    const int tmx3 = __builtin_amdgcn_readfirstlane(snitL[48]);
    const int maxN = __builtin_amdgcn_readfirstlane(snitL[0]);

    // physical rows for my A-fragment lanes, per M-tile (slot = (mt<<4)+(l&15))
    const int aPh0 = permL[ 0 + (l&15)];
    const int aPh1 = permL[16 + (l&15)];
    const int aPh2 = permL[32 + (l&15)];
    const int aPh3 = permL[48 + (l&15)];

    const float bi_ = bias[hcol], bf_ = bias[HH+hcol], bg_ = bias[2*HH+hcol], bo_ = bias[3*HH+hcol];

    const int cprod = bid >> 5;                  // chunk this block produces
    u32* myFlagW = flg + cprod*32 + (bid & 31);  // my flag word
    const u32* pollP = flg + w*32 + (l & 31);    // wave w polls chunk w's line

    float cst = 0.0f;
    // h-phase ping-pong buffers (named, fully static)
    short8 hA0h,hA0l,hA1h,hA1l,hA2h,hA2l,hA3h,hA3l;
    short8 hB0h,hB0l,hB1h,hB1l,hB2h,hB2l,hB3h,hB3l;

#define XC2(P, v0, v1, BH, BL) { \
    short8 ph, pl; \
    _Pragma("unroll") for (int e=0;e<8;++e){ \
        float fv = (e<4) ? v0[e] : v1[e-4]; \
        u16 hb = bf16r(fv); ph[e]=(short)hb; pl[e]=(short)bf16r(fv - bf16f(hb)); } \
    P##0 = __builtin_amdgcn_mfma_f32_16x16x32_bf16(ph, BH, P##0, 0,0,0); \
    P##1 = __builtin_amdgcn_mfma_f32_16x16x32_bf16(pl, BH, P##1, 0,0,0); \
    P##2 = __builtin_amdgcn_mfma_f32_16x16x32_bf16(ph, BL, P##2, 0,0,0); }

// x phase for M-tile: A row = PHYSICAL row (APH), B from registers
#define XPH(P, APH) { \
    const float* xp_ = seq + (size_t)(APH)*(TT*II) + (size_t)t*II + (w<<6) + ag; \
    f32x4 x0 = *(const f32x4*)xp_,      x1 = *(const f32x4*)(xp_+4); \
    f32x4 x2 = *(const f32x4*)(xp_+32), x3 = *(const f32x4*)(xp_+36); \
    XC2(P, x0, x1, bx0h, bx0l); \
    XC2(P, x2, x3, bx1h, bx1l); }

// h loads for M-tile mt into ping-pong buffer BUF (slot-indexed h ring)
#define HLDP(BUF, mt) { \
    const u16* hp_ = hiP + (size_t)(((mt)<<4)+(l&15))*HH + (w<<7) + ag; \
    BUF##0h = *(const short8*)hp_;       BUF##0l = *(const short8*)(hp_+65536); \
    BUF##1h = *(const short8*)(hp_+32);  BUF##1l = *(const short8*)(hp_+32+65536); \
    BUF##2h = *(const short8*)(hp_+64);  BUF##2l = *(const short8*)(hp_+64+65536); \
    BUF##3h = *(const short8*)(hp_+96);  BUF##3l = *(const short8*)(hp_+96+65536); }

// h MFMAs from buffer BUF into accumulator set P (B from registers)
#define HMMP(BUF, P) { \
    P##0 = __builtin_amdgcn_mfma_f32_16x16x32_bf16(BUF##0h, bh0h, P##0, 0,0,0); \
    P##1 = __builtin_amdgcn_mfma_f32_16x16x32_bf16(BUF##0l, bh0h, P##1, 0,0,0); \
    P##2 = __builtin_amdgcn_mfma_f32_16x16x32_bf16(BUF##0h, bh0l, P##2, 0,0,0); \
    P##0 = __builtin_amdgcn_mfma_f32_16x16x32_bf16(BUF##1h, bh1h, P##0, 0,0,0); \
    P##1 = __builtin_amdgcn_mfma_f32_16x16x32_bf16(BUF##1l, bh1h, P##1, 0,0,0); \
    P##2 = __builtin_amdgcn_mfma_f32_16x16x32_bf16(BUF##1h, bh1l, P##2, 0,0,0); \
    P##0 = __builtin_amdgcn_mfma_f32_16x16x32_bf16(BUF##2h, bh2h, P##0, 0,0,0); \
    P##1 = __builtin_amdgcn_mfma_f32_16x16x32_bf16(BUF##2l, bh2h, P##1, 0,0,0); \
    P##2 = __builtin_amdgcn_mfma_f32_16x16x32_bf16(BUF##2h, bh2l, P##2, 0,0,0); \
    P##0 = __builtin_amdgcn_mfma_f32_16x16x32_bf16(BUF##3h, bh3h, P##0, 0,0,0); \
    P##1 = __builtin_amdgcn_mfma_f32_16x16x32_bf16(BUF##3l, bh3h, P##1, 0,0,0); \
    P##2 = __builtin_amdgcn_mfma_f32_16x16x32_bf16(BUF##3h, bh3l, P##2, 0,0,0); }

#define EXW(P, mt) { \
    const int n_ = l & 15; \
    const int r0_ = ((mt)<<4) + ((l>>4)<<2); \
    float* e_ = exs + w*1024 + r0_*16 + n_; \
    _Pragma("unroll") for (int j=0;j<4;++j) \
        e_[j*16] = P##0[j] + P##1[j] + P##2[j]; }

    for (int t = 0; t <= maxN; ++t) {
        const u16* hiP = hbuf + (size_t)(t&1)*131072;
        u16*       hiN = hbuf + (size_t)(1-(t&1))*131072;
        u16*       loN = hiN + 65536;

        f32x4 z4 = {0.f,0.f,0.f,0.f};
        f32x4 aA0=z4,aA1=z4,aA2=z4, aB0=z4,aB1=z4,aB2=z4;
        f32x4 aC0=z4,aC1=z4,aC2=z4, aD0=z4,aD1=z4,aD2=z4;

        // ---- x GEMM: this wave's 64-k slice, ACTIVE tiles only (pre-wait) ----
        XPH(aA, aPh0)
        if (t <= tmx1) { XPH(aB, aPh1) }
        if (t <= tmx2) { XPH(aC, aPh2) }
        if (t <= tmx3) { XPH(aD, aPh3) }

        // ---- RMW-free chunk wait, then h GEMM: pipelined across active tiles ----
        if (t > 0) {
            for (;;) {
                u32 v = LD_AG(pollP);
                if (__all((int)v >= t)) break;
                __builtin_amdgcn_s_sleep(1);
            }
            HLDP(hA, 0)
            if (t <= tmx1) { HLDP(hB, 1) }
            HMMP(hA, aA)
            if (t <= tmx1) {
                if (t <= tmx2) { HLDP(hA, 2) }
                HMMP(hB, aB)
                if (t <= tmx2) {
                    if (t <= tmx3) { HLDP(hB, 3) }
                    HMMP(hA, aC)
                    if (t <= tmx3) { HMMP(hB, aD) }
                }
            }
        }

        // ---- exchange: wave w writes its k-slice partials (active tiles) ----
        EXW(aA,0)
        if (t <= tmx1) { EXW(aB,1) }
        if (t <= tmx2) { EXW(aC,2) }
        if (t <= tmx3) { EXW(aD,3) }
        __syncthreads();

        // ---- gate (tid<256, active slots): sum 8 k-slices + bias ----
        if (tid < 256 && t <= myNs) {
            const float* e0 = exs + rEx*16 + ccEx;
            float z0 = bi_, z1 = bf_, z2 = bg_, z3 = bo_;
            #pragma unroll
            for (int ww = 0; ww < 8; ++ww) {
                const float* e_ = e0 + ww*1024;
                z0 += e_[0]; z1 += e_[4]; z2 += e_[8]; z3 += e_[12];
            }
            float iv = sigf(z0), fv = sigf(z1), gv = tanhf(z2), ov = sigf(z3);
            cst = fv*cst + iv*gv;
            float h = ov * tanhf(cst);
            u16 hb = bf16r(h);
            u16 lb = bf16r(h - bf16f(hb));
            ST_AG(&hiN[(size_t)rEx*HH + hcol], hb);     // slot-indexed
            ST_AG(&loN[(size_t)rEx*HH + hcol], lb);
            if (t == myNs) ST_AG(&uq[(size_t)prG*HH + hcol], h);  // physical row
        }

        // ---- publish: vmcnt -> flag store (no RMW) + one fence per block/step ----
        asm volatile("s_waitcnt vmcnt(0)" ::: "memory");
        __syncthreads();
        if (tid == 0) {
            ST_AG(myFlagW, (u32)(t + 1));
            __builtin_amdgcn_fence(__ATOMIC_ACQUIRE, "agent");
        }
        __syncthreads();
    }

#undef XC2
#undef XPH
#undef HLDP
#undef HMMP
#undef EXW

    // ---------- tail: all blocks done (=> all uq stored), fence, then VQ ----------
    bar_arrive(barT, bid, tid, 1);
    bar_wait(barT, bid, tid, 1);      // fence inside -> plain uq reads OK

    // ---------- VQ: distance^2 matrix [64][512] ----------
    {
        const int wid = bid*8 + w;
        for (int p = wid*16; p < wid*16 + 16; ++p) {
            int rr = p >> 9;
            int kk = p & 511;
            const u64* u8p = (const u64*)(uq + (size_t)rr*HH);
            const f32x4* c4 = (const f32x4*)(cb + (size_t)kk*HH);
            float s = 0.0f;
            #pragma unroll
            for (int q = 0; q < 4; ++q) {
                u64 e0 = u8p[2*(l + q*64)];
                u64 e1 = u8p[2*(l + q*64) + 1];
                f32x4 b = c4[l + q*64];
                float a0 = __uint_as_float((u32)e0), a1 = __uint_as_float((u32)(e0>>32));
                float a2 = __uint_as_float((u32)e1), a3 = __uint_as_float((u32)(e1>>32));
                float d0 = a0-b[0], d1 = a1-b[1], d2 = a2-b[2], d3 = a3-b[3];
                s += d0*d0 + d1*d1 + d2*d2 + d3*d3;
            }
            #pragma unroll
            for (int off = 32; off > 0; off >>= 1) s += __shfl_xor(s, off, 64);
            if (l == 0) ST_AG(&dist[(size_t)rr*KCB + kk], s);
        }
    }
    bar_arrive(barT, bid, tid, 2);
    bar_wait(barT, bid, tid, 2);      // fence inside -> plain dist reads OK

    // ---------- argmin + emit outputs (blocks 0..63, one row each) ----------
    if (bid < BB) {
        const int rr = bid;
        if (tid < 64) {
            float best = 3.4e38f;
            int   bi   = 0;
            for (int kk = tid; kk < KCB; kk += 64) {
                float v = dist[(size_t)rr*KCB + kk];
                if (v < best) { best = v; bi = kk; }
            }
            #pragma unroll
            for (int off = 32; off > 0; off >>= 1) {
                float ovv = __shfl_xor(best, off, 64);
                int   oii = __shfl_xor(bi,   off, 64);
                if (ovv < best || (ovv == best && oii < bi)) { best = ovv; bi = oii; }
            }
            if (tid == 0) { sBest = bi; out[rr] = (float)bi; }
        }
        __syncthreads();
        const int bk = sBest;
        const f32x4* c4 = (const f32x4*)(cb + (size_t)bk*HH);
        f32x4*       q4 = (f32x4*)(qz + (size_t)rr*HH);
        for (int d = tid; d < HH/4; d += 512) q4[d] = c4[d];
    }
}

extern "C" void kernel_launch(void* const* d_in, const int* in_sizes, int n_in,
                              void* d_out, int out_size, void* d_ws, size_t ws_size,
                              hipStream_t stream) {
    const float* seq  = (const float*)d_in[0];
    const int*   nit  = (const int*)  d_in[1];
    const float* Wx   = (const float*)d_in[2];
    const float* Wh   = (const float*)d_in[3];
    const float* bias = (const float*)d_in[4];
    const float* cb   = (const float*)d_in[5];
    float* out = (float*)d_out;
    float* ws  = (float*)d_ws;

    void* args[] = { &seq, &nit, &Wx, &Wh, &bias, &cb, &out, &ws };
    hipLaunchCooperativeKernel((void*)lstm_vq, dim3(256), dim3(512), args, 0, stream);
}